// Round 1
// baseline (593.325 us; speedup 1.0000x reference)
//
#include <hip/hip_runtime.h>
#include <hip/hip_bf16.h>
#include <math.h>

// A1SparseCoding: STFT(512,160,hann,center=False) -> |.| -> per-sample norm ->
// LCA (50 iters, lam=0.5, tau=10) -> softshrink(u)
// B=8192, SEG=3200, T=17 frames, F=257 freqs, K=17*257=4369 (pad 4384), N=128 bases.
//
// spec stored [b][t*257+f] (k-permuted vs reference [f*17+t]); D's columns are
// permuted identically, so all dot products / moments are unchanged.

#define PI_F 3.14159265358979323846f

typedef short bf16x8 __attribute__((ext_vector_type(8)));
typedef float f32x4  __attribute__((ext_vector_type(4)));

__device__ __forceinline__ unsigned short f2bf(float f){
  unsigned int u = __float_as_uint(f);
  u += 0x7FFFu + ((u >> 16) & 1u);      // RNE; inputs finite
  return (unsigned short)(u >> 16);
}
__device__ __forceinline__ float bfhi(unsigned int w){ return __uint_as_float(w & 0xFFFF0000u); }
__device__ __forceinline__ float bflo(unsigned int w){ return __uint_as_float(w << 16); }
__device__ __forceinline__ float sshrink(float u){
  float a = fabsf(u) - 0.5f;
  return a > 0.0f ? copysignf(a, u) : 0.0f;
}

// ---------------- P0: window + twiddle tables ----------------
__global__ void k_tables(float* __restrict__ win, float2* __restrict__ lut){
  int p = blockIdx.x*blockDim.x + threadIdx.x;
  if (p < 512){
    win[p] = 0.5f - 0.5f*cosf(2.0f*PI_F*(float)p/512.0f);   // periodic hann
    float ang = -2.0f*PI_F*(float)p/512.0f;
    lut[p] = make_float2(cosf(ang), sinf(ang));             // W_512^p
  }
}

// ---------------- P1: Dbf[n][k'] = bf16(D[n][perm(k')]), k'=t*257+f, pad->0 ----
__global__ __launch_bounds__(256) void k_dperm(const float* __restrict__ D,
    unsigned short* __restrict__ Dbf){
  int n = blockIdx.x;
  for (int k = threadIdx.x; k < 4384; k += 256){
    unsigned short v = 0;
    if (k < 4369){
      int tt = k / 257, f = k - tt*257;
      v = f2bf(D[(size_t)n*4369 + f*17 + tt]);
    }
    Dbf[(size_t)n*4384 + k] = v;
  }
}

// ---------------- P1b: Dt[k'][n] fp32 (for gram/rowsum), pad rows -> 0 -------
__global__ __launch_bounds__(128) void k_dt(const float* __restrict__ D,
    float* __restrict__ Dt){
  int kb = blockIdx.x;          // 137 blocks x 32 k
  int n = threadIdx.x;          // 128
  for (int i = 0; i < 32; i++){
    int k = kb*32 + i;
    float v = 0.0f;
    if (k < 4369){
      int tt = k / 257, f = k - tt*257;
      v = D[(size_t)n*4369 + f*17 + tt];
    }
    Dt[(size_t)k*128 + n] = v;
  }
}

// ---------------- P2: rowsum[n] = sum_k D[n][k] ------------------------------
__global__ __launch_bounds__(64) void k_rowsum(const float* __restrict__ Dt,
    float* __restrict__ rowsum){
  int n = blockIdx.x, lane = threadIdx.x;
  float s = 0.0f;
  for (int k = lane; k < 4384; k += 64) s += Dt[(size_t)k*128 + n]; // pad=0
  #pragma unroll
  for (int off = 32; off > 0; off >>= 1) s += __shfl_down(s, off);
  if (lane == 0) rowsum[n] = s;
}

// ---------------- P3: gram_bf[x][y] = bf16(D·Dᵀ - I), stride 136 -------------
__global__ __launch_bounds__(128) void k_gram(const float* __restrict__ Dt,
    unsigned short* __restrict__ gram_bf){
  const int x = blockIdx.x, y = threadIdx.x;
  float a0=0.f,a1=0.f,a2=0.f,a3=0.f;
  for (int k = 0; k < 4384; k += 4){     // pad rows are zero
    a0 = fmaf(Dt[(size_t)(k+0)*128 + x], Dt[(size_t)(k+0)*128 + y], a0);
    a1 = fmaf(Dt[(size_t)(k+1)*128 + x], Dt[(size_t)(k+1)*128 + y], a1);
    a2 = fmaf(Dt[(size_t)(k+2)*128 + x], Dt[(size_t)(k+2)*128 + y], a2);
    a3 = fmaf(Dt[(size_t)(k+3)*128 + x], Dt[(size_t)(k+3)*128 + y], a3);
  }
  float g = (a0+a1)+(a2+a3);
  if (x == y) g -= 1.0f;                 // identical summation order for (x,y)/(y,x) -> exactly symmetric
  gram_bf[x*136 + y] = f2bf(g);
}

// ---------------- radix-8 butterfly (DIT), in registers ----------------------
__device__ __forceinline__ void dft8(float xr[8], float xi[8]){
  const float C = 0.70710678118654752f;
  float t0r = xr[0]+xr[4], t0i = xi[0]+xi[4];
  float t1r = xr[0]-xr[4], t1i = xi[0]-xi[4];
  float t2r = xr[2]+xr[6], t2i = xi[2]+xi[6];
  float t3r = xr[2]-xr[6], t3i = xi[2]-xi[6];
  float e0r = t0r+t2r, e0i = t0i+t2i;
  float e2r = t0r-t2r, e2i = t0i-t2i;
  float e1r = t1r+t3i, e1i = t1i-t3r;    // t1 - i*t3
  float e3r = t1r-t3i, e3i = t1i+t3r;    // t1 + i*t3
  float s0r = xr[1]+xr[5], s0i = xi[1]+xi[5];
  float s1r = xr[1]-xr[5], s1i = xi[1]-xi[5];
  float s2r = xr[3]+xr[7], s2i = xi[3]+xi[7];
  float s3r = xr[3]-xr[7], s3i = xi[3]-xi[7];
  float o0r = s0r+s2r, o0i = s0i+s2i;
  float o2r = s0r-s2r, o2i = s0i-s2i;
  float o1r = s1r+s3i, o1i = s1i-s3r;
  float o3r = s1r-s3i, o3i = s1i+s3r;
  xr[0] = e0r+o0r; xi[0] = e0i+o0i;
  xr[4] = e0r-o0r; xi[4] = e0i-o0i;
  float w1r = C*(o1r+o1i), w1i = C*(o1i-o1r);   // w8^1 * o1
  xr[1] = e1r+w1r; xi[1] = e1i+w1i;
  xr[5] = e1r-w1r; xi[5] = e1i-w1i;
  xr[2] = e2r+o2i; xi[2] = e2i-o2r;             // -i * o2
  xr[6] = e2r-o2i; xi[6] = e2i+o2r;
  float w3r = C*(o3i-o3r), w3i = -C*(o3r+o3i);  // w8^3 * o3
  xr[3] = e3r+w3r; xi[3] = e3i+w3i;
  xr[7] = e3r-w3r; xi[7] = e3i-w3i;
}

// ---------------- K1: STFT magnitude, radix-8 (1 wave = 1 frame) -------------
// LDS layout padded: element i at loc i + (i>>3)  (conflict-free strided-8 access)
__global__ __launch_bounds__(64) void k_stft(const float* __restrict__ audio,
    const float* __restrict__ win, const float2* __restrict__ lut,
    unsigned short* __restrict__ spec){
  const int frame = blockIdx.x;
  const int b = frame / 17;
  const int t = frame - b*17;
  const int L = threadIdx.x;
  __shared__ float re[576], im[576];
  const float* src = audio + (size_t)b*3200 + t*160;
  float xr[8], xi[8];
  // fused digit-reversed load + stage 0 (m=8, twiddles = 1)
  #pragma unroll
  for (int e = 0; e < 8; e++){
    int idx = 8*L + e;
    int r9 = ((idx & 7) << 6) | (idx & 56) | (idx >> 6);  // base-8 digit reversal
    float v = src[r9] * win[r9];
    xr[e] = v; xi[e] = 0.0f;
  }
  dft8(xr, xi);
  #pragma unroll
  for (int f = 0; f < 8; f++){
    int i = 8*L + f, loc = i + (i >> 3);
    re[loc] = xr[f]; im[loc] = xi[f];
  }
  __syncthreads();
  // stage 1: m=64
  {
    int j = L & 7, g = L >> 3;
    int base = g*64 + j;
    #pragma unroll
    for (int e = 0; e < 8; e++){
      int i = base + 8*e, loc = i + (i >> 3);
      xr[e] = re[loc]; xi[e] = im[loc];
    }
    #pragma unroll
    for (int e = 1; e < 8; e++){
      float2 w = lut[8*j*e];                  // W_64^(j e) = W_512^(8 j e)
      float a = xr[e], bb = xi[e];
      xr[e] = a*w.x - bb*w.y;
      xi[e] = a*w.y + bb*w.x;
    }
    dft8(xr, xi);
    #pragma unroll
    for (int f = 0; f < 8; f++){
      int i = base + 8*f, loc = i + (i >> 3);
      re[loc] = xr[f]; im[loc] = xi[f];
    }
  }
  __syncthreads();
  // stage 2: m=512, outputs k = L + 64*f ; magnitude written directly
  {
    int j = L;
    #pragma unroll
    for (int e = 0; e < 8; e++){
      int loc = j + (j >> 3) + 72*e;
      xr[e] = re[loc]; xi[e] = im[loc];
    }
    #pragma unroll
    for (int e = 1; e < 8; e++){
      float2 w = lut[j*e];                    // W_512^(j e), j*e <= 441
      float a = xr[e], bb = xi[e];
      xr[e] = a*w.x - bb*w.y;
      xi[e] = a*w.y + bb*w.x;
    }
    dft8(xr, xi);
    unsigned short* dst = spec + (size_t)b*4384 + t*257;
    #pragma unroll
    for (int f = 0; f < 4; f++){
      float m2 = xr[f]*xr[f] + xi[f]*xi[f];
      dst[L + 64*f] = f2bf(sqrtf(m2));        // k = L + 64f <= 255
    }
    if (L == 0){
      float m2 = xr[4]*xr[4] + xi[4]*xi[4];
      dst[256] = f2bf(sqrtf(m2));             // Nyquist-adjacent k=256
    }
    if (t == 0 && L < 15) spec[(size_t)b*4384 + 4369 + L] = 0;  // zero k-pad
  }
}

// ---------------- K2: per-sample mean / 1/(std+1e-8) (ddof=1) ----------------
__global__ __launch_bounds__(256) void k_moments(const unsigned short* __restrict__ spec,
    float* __restrict__ mu, float* __restrict__ inv){
  const int b = blockIdx.x;
  const uint4* row = (const uint4*)(spec + (size_t)b*4384);
  float s1 = 0.f, s2 = 0.f;
  for (int i = threadIdx.x; i < 548; i += 256){   // 548*8 = 4384, pad zeros harmless
    uint4 v = row[i];
    unsigned int wd[4] = {v.x, v.y, v.z, v.w};
    #pragma unroll
    for (int u = 0; u < 4; u++){
      float a = bflo(wd[u]);
      float c = bfhi(wd[u]);
      s1 += a + c; s2 += a*a + c*c;
    }
  }
  #pragma unroll
  for (int off = 32; off > 0; off >>= 1){
    s1 += __shfl_down(s1, off);
    s2 += __shfl_down(s2, off);
  }
  __shared__ float r1[4], r2[4];
  int w = threadIdx.x >> 6, lane = threadIdx.x & 63;
  if (lane == 0){ r1[w] = s1; r2[w] = s2; }
  __syncthreads();
  if (threadIdx.x == 0){
    float S1 = (r1[0]+r1[1])+(r1[2]+r1[3]);
    float S2 = (r2[0]+r2[1])+(r2[2]+r2[3]);
    float m = S1 / 4369.0f;
    float var = (S2 - S1*S1/4369.0f) / 4368.0f;
    var = fmaxf(var, 0.0f);
    mu[b] = m;
    inv[b] = 1.0f / (sqrtf(var) + 1e-8f);
  }
}

// ---------------- K4: partial GEMM spec·Dᵀ, MFMA, frags direct from global ---
// grid (256 mtiles, 4 ksplit), 128 thr. part[ks][n][m] fp32.
__global__ __launch_bounds__(128) void k_gemm(const unsigned short* __restrict__ spec,
    const unsigned short* __restrict__ Dbf, float* __restrict__ part){
  const int mtile = blockIdx.x;
  const int ks = blockIdx.y;
  const int wv = threadIdx.x >> 6;
  const int lane = threadIdx.x & 63;
  const int c = lane & 15, q = lane >> 4;
  const int m = mtile*32 + wv*16 + c;
  const unsigned short* ap = spec + (size_t)m*4384 + q*8;
  const int t0 = ks*35, t1 = (ks == 3) ? 137 : (ks*35 + 35);
  f32x4 acc[8];
  #pragma unroll
  for (int nt = 0; nt < 8; nt++) acc[nt] = (f32x4){0.f,0.f,0.f,0.f};
  for (int tt = t0; tt < t1; tt++){
    const int k0 = tt*32;
    bf16x8 af = *(const bf16x8*)(ap + k0);                  // A[m=c][k=q*8+j]
    #pragma unroll
    for (int nt = 0; nt < 8; nt++){
      bf16x8 bfr = *(const bf16x8*)(Dbf + (size_t)(nt*16 + c)*4384 + k0 + q*8); // B[k][n=c]
      acc[nt] = __builtin_amdgcn_mfma_f32_16x16x32_bf16(af, bfr, acc[nt], 0, 0, 0);
    }
  }
  // C/D: row(m) = q*4+r, col(n) = c  ->  part[ks][n][m], float4 over m
  float* base = part + (size_t)ks*1048576 + (size_t)mtile*32 + wv*16 + q*4;
  #pragma unroll
  for (int nt = 0; nt < 8; nt++)
    *(f32x4*)(base + (size_t)(nt*16 + c)*8192) = acc[nt];
}

// ---------------- K5: LCA, 50 iters. Transposed algebra rᵀ = G·aᵀ -----------
// block = 128 thr (2 waves x 16 samples), 256 blocks. G,a in LDS (stride 136).
// U frag semantics: U[rt][r] = u[sample = blk*32+wv*16+c][n = rt*16+q*4+r]
__global__ __launch_bounds__(128) void k_lca(const float* __restrict__ part,
    const unsigned short* __restrict__ gram_bf, const float* __restrict__ rowsum,
    const float* __restrict__ mu, const float* __restrict__ inv,
    float* __restrict__ out){
  __shared__ unsigned short G[128*136];
  __shared__ unsigned short A[32*136];
  const int tid = threadIdx.x;
  for (int i = tid; i < 2176; i += 128)                 // 128*136/8
    ((uint4*)G)[i] = ((const uint4*)gram_bf)[i];
  const int wv = tid >> 6, lane = tid & 63;
  const int c = lane & 15, q = lane >> 4;
  const int sl = wv*16 + c;
  const int sg = blockIdx.x*32 + sl;
  const float mus = mu[sg], invs = inv[sg];
  f32x4 U[8], Bb[8];
  #pragma unroll
  for (int rt = 0; rt < 8; rt++){
    #pragma unroll
    for (int r = 0; r < 4; r++){
      int n = rt*16 + q*4 + r;
      float S = part[(size_t)n*8192 + sg]
              + part[(size_t)1048576 + (size_t)n*8192 + sg]
              + part[(size_t)2097152 + (size_t)n*8192 + sg]
              + part[(size_t)3145728 + (size_t)n*8192 + sg];
      Bb[rt][r] = invs * (S - mus * rowsum[n]);         // b = inv*(spec·Dᵀ - mu*rowsumD)
      U[rt][r] = 0.0f;
    }
  }
  for (int it = 0; it < 50; it++){
    // a = softshrink(u): 4 consecutive n per reg-quad -> ushort4 store
    #pragma unroll
    for (int rt = 0; rt < 8; rt++){
      ushort4 pk;
      pk.x = f2bf(sshrink(U[rt][0]));
      pk.y = f2bf(sshrink(U[rt][1]));
      pk.z = f2bf(sshrink(U[rt][2]));
      pk.w = f2bf(sshrink(U[rt][3]));
      *(ushort4*)(A + sl*136 + rt*16 + q*4) = pk;
    }
    __syncthreads();
    bf16x8 af[4];
    #pragma unroll
    for (int kt = 0; kt < 4; kt++)                      // B-frag: aᵀ[k][s=c]
      af[kt] = *(const bf16x8*)(A + (size_t)(wv*16 + c)*136 + kt*32 + q*8);
    f32x4 R[8];
    #pragma unroll
    for (int rt = 0; rt < 8; rt++) R[rt] = (f32x4){0.f,0.f,0.f,0.f};
    #pragma unroll
    for (int rt = 0; rt < 8; rt++){
      #pragma unroll
      for (int kt = 0; kt < 4; kt++){
        bf16x8 gf = *(const bf16x8*)(G + (size_t)(rt*16 + c)*136 + kt*32 + q*8); // A-frag: G[n'=c][k]
        R[rt] = __builtin_amdgcn_mfma_f32_16x16x32_bf16(gf, af[kt], R[rt], 0, 0, 0);
      }
    }
    #pragma unroll
    for (int rt = 0; rt < 8; rt++){
      #pragma unroll
      for (int r = 0; r < 4; r++){
        float u = U[rt][r];
        U[rt][r] = u + (Bb[rt][r] - u - R[rt][r]) * 0.1f;
      }
    }
    __syncthreads();
  }
  #pragma unroll
  for (int rt = 0; rt < 8; rt++){
    float4 o;
    o.x = sshrink(U[rt][0]);
    o.y = sshrink(U[rt][1]);
    o.z = sshrink(U[rt][2]);
    o.w = sshrink(U[rt][3]);
    *(float4*)(out + (size_t)sg*128 + rt*16 + q*4) = o;
  }
}

// ---------------- launch ----------------
extern "C" void kernel_launch(void* const* d_in, const int* in_sizes, int n_in,
                              void* d_out, int out_size, void* d_ws, size_t ws_size,
                              hipStream_t stream){
  const float* audio = (const float*)d_in[0];   // 8192*3200
  const float* D     = (const float*)d_in[1];   // 128*4369
  float* out = (float*)d_out;                   // 8192*128 f32
  char* ws = (char*)d_ws;
  // workspace layout (256B-aligned), total ~92.1 MB
  unsigned short* spec   = (unsigned short*)(ws);               // 8192*4384*2 = 71,827,456
  float*          part   = (float*)(ws + 71827456);             // 4*128*8192*4 = 16,777,216
  unsigned short* Dbf    = (unsigned short*)(ws + 88604672);    // 128*4384*2 = 1,122,304
  float*          Dt     = (float*)(ws + 89726976);             // 4384*128*4 = 2,244,608
  unsigned short* gram   = (unsigned short*)(ws + 91971584);    // 128*136*2 = 34,816
  float*          rowsum = (float*)(ws + 92006400);             // 512
  float*          mu     = (float*)(ws + 92006912);             // 32,768
  float*          inv    = (float*)(ws + 92039680);             // 32,768
  float*          win    = (float*)(ws + 92072448);             // 2,048
  float2*         lut    = (float2*)(ws + 92074496);            // 4,096

  k_tables <<<2, 256, 0, stream>>>(win, lut);
  k_dperm  <<<128, 256, 0, stream>>>(D, Dbf);
  k_dt     <<<137, 128, 0, stream>>>(D, Dt);
  k_rowsum <<<128, 64, 0, stream>>>(Dt, rowsum);
  k_gram   <<<128, 128, 0, stream>>>(Dt, gram);
  k_stft   <<<139264, 64, 0, stream>>>(audio, win, lut, spec);
  k_moments<<<8192, 256, 0, stream>>>(spec, mu, inv);
  k_gemm   <<<dim3(256, 4, 1), 128, 0, stream>>>(spec, Dbf, part);
  k_lca    <<<256, 128, 0, stream>>>(part, gram, rowsum, mu, inv, out);
}

// Round 2
// 410.033 us; speedup vs baseline: 1.4470x; 1.4470x over previous
//
#include <hip/hip_runtime.h>
#include <hip/hip_bf16.h>
#include <math.h>

// A1SparseCoding: STFT(512,160,hann,center=False) -> |.| -> per-sample norm ->
// LCA (50 iters, lam=0.5, tau=10) -> softshrink(u)
// B=8192, SEG=3200, T=17 frames, F=257 freqs, K=17*257=4369 (pad 4384), N=128 bases.
// spec stored [b][t*257+f]; D's columns permuted identically (dot products invariant).
// STFT: two real frames packed as one complex FFT (a+ib), radix-8 DIT, fp32.
// Moments (mean/std) accumulated from fp32 magnitudes via atomics in k_stft.

#define PI_F 3.14159265358979323846f

typedef short bf16x8 __attribute__((ext_vector_type(8)));
typedef float f32x4  __attribute__((ext_vector_type(4)));

__device__ __forceinline__ unsigned short f2bf(float f){
  unsigned int u = __float_as_uint(f);
  u += 0x7FFFu + ((u >> 16) & 1u);      // RNE; inputs finite
  return (unsigned short)(u >> 16);
}
__device__ __forceinline__ float sshrink(float u){
  float a = fabsf(u) - 0.5f;
  return a > 0.0f ? copysignf(a, u) : 0.0f;
}

// ---------------- P0: digit-reversed window + twiddle tables ----------------
__global__ void k_tables(float* __restrict__ win_dr, float2* __restrict__ lut){
  int p = blockIdx.x*blockDim.x + threadIdx.x;
  if (p < 512){
    int r9 = ((p & 7) << 6) | (p & 56) | (p >> 6);        // base-8 digit reversal
    win_dr[p] = 0.5f - 0.5f*cosf(2.0f*PI_F*(float)r9/512.0f); // periodic hann, pre-permuted
    float ang = -2.0f*PI_F*(float)p/512.0f;
    lut[p] = make_float2(cosf(ang), sinf(ang));           // W_512^p
  }
}

// ---------------- P1: D prep (coalesced read; scattered writes) -------------
// Dbf[n][k'] bf16 (k' = t*257+f, pad->0); Dt[k][n] fp32 natural k (pad rows 0);
// rowsum[n] = sum_k D[n][k]  (block reduction, deterministic).
__global__ __launch_bounds__(256) void k_dprep(const float* __restrict__ D,
    unsigned short* __restrict__ Dbf, float* __restrict__ Dt,
    float* __restrict__ rowsum){
  const int n = blockIdx.x;
  float acc = 0.0f;
  for (int k = threadIdx.x; k < 4369; k += 256){
    float v = D[(size_t)n*4369 + k];          // coalesced
    int f = k / 17, t = k - f*17;             // natural index = f*17 + t
    int kp = t*257 + f;
    Dbf[(size_t)n*4384 + kp] = f2bf(v);
    Dt[(size_t)k*128 + n] = v;
    acc += v;
  }
  if (threadIdx.x < 15) Dbf[(size_t)n*4384 + 4369 + threadIdx.x] = 0;
  if (n == 0){
    for (int i = threadIdx.x; i < 15*128; i += 256) Dt[4369*128 + i] = 0.0f;
  }
  __shared__ float rs[256];
  rs[threadIdx.x] = acc;
  __syncthreads();
  #pragma unroll
  for (int s = 128; s > 0; s >>= 1){
    if (threadIdx.x < s) rs[threadIdx.x] += rs[threadIdx.x + s];
    __syncthreads();
  }
  if (threadIdx.x == 0) rowsum[n] = rs[0];
}

// ---------------- P2: gram partials over 4 k-chunks + finalize --------------
__global__ __launch_bounds__(128) void k_gram_part(const float* __restrict__ Dt,
    float* __restrict__ pg){
  const int x = blockIdx.x, ks = blockIdx.y, y = threadIdx.x;
  const float* px = Dt + (size_t)ks*1096*128 + x;
  const float* py = Dt + (size_t)ks*1096*128 + y;
  float a0=0.f,a1=0.f,a2=0.f,a3=0.f;
  for (int k = 0; k < 1096; k += 4){          // pad rows are zero
    a0 = fmaf(px[(size_t)(k+0)*128], py[(size_t)(k+0)*128], a0);
    a1 = fmaf(px[(size_t)(k+1)*128], py[(size_t)(k+1)*128], a1);
    a2 = fmaf(px[(size_t)(k+2)*128], py[(size_t)(k+2)*128], a2);
    a3 = fmaf(px[(size_t)(k+3)*128], py[(size_t)(k+3)*128], a3);
  }
  pg[((size_t)ks*128 + x)*128 + y] = (a0+a1)+(a2+a3);
}
// identical order for (x,y)/(y,x) at every step -> gram exactly symmetric
__global__ __launch_bounds__(128) void k_gram_fin(const float* __restrict__ pg,
    unsigned short* __restrict__ gram_bf){
  const int x = blockIdx.x, y = threadIdx.x;
  float g = (pg[(size_t)x*128+y] + pg[(size_t)(128+x)*128+y])
          + (pg[(size_t)(256+x)*128+y] + pg[(size_t)(384+x)*128+y]);
  if (x == y) g -= 1.0f;
  gram_bf[x*136 + y] = f2bf(g);
}

// ---------------- radix-8 butterfly (DIT), in registers ----------------------
__device__ __forceinline__ void dft8(float xr[8], float xi[8]){
  const float C = 0.70710678118654752f;
  float t0r = xr[0]+xr[4], t0i = xi[0]+xi[4];
  float t1r = xr[0]-xr[4], t1i = xi[0]-xi[4];
  float t2r = xr[2]+xr[6], t2i = xi[2]+xi[6];
  float t3r = xr[2]-xr[6], t3i = xi[2]-xi[6];
  float e0r = t0r+t2r, e0i = t0i+t2i;
  float e2r = t0r-t2r, e2i = t0i-t2i;
  float e1r = t1r+t3i, e1i = t1i-t3r;    // t1 - i*t3
  float e3r = t1r-t3i, e3i = t1i+t3r;    // t1 + i*t3
  float s0r = xr[1]+xr[5], s0i = xi[1]+xi[5];
  float s1r = xr[1]-xr[5], s1i = xi[1]-xi[5];
  float s2r = xr[3]+xr[7], s2i = xi[3]+xi[7];
  float s3r = xr[3]-xr[7], s3i = xi[3]-xi[7];
  float o0r = s0r+s2r, o0i = s0i+s2i;
  float o2r = s0r-s2r, o2i = s0i-s2i;
  float o1r = s1r+s3i, o1i = s1i-s3r;
  float o3r = s1r-s3i, o3i = s1i+s3r;
  xr[0] = e0r+o0r; xi[0] = e0i+o0i;
  xr[4] = e0r-o0r; xi[4] = e0i-o0i;
  float w1r = C*(o1r+o1i), w1i = C*(o1i-o1r);   // w8^1 * o1
  xr[1] = e1r+w1r; xi[1] = e1i+w1i;
  xr[5] = e1r-w1r; xi[5] = e1i-w1i;
  xr[2] = e2r+o2i; xi[2] = e2i-o2r;             // -i * o2
  xr[6] = e2r-o2i; xi[6] = e2i+o2r;
  float w3r = C*(o3i-o3r), w3i = -C*(o3r+o3i);  // w8^3 * o3
  xr[3] = e3r+w3r; xi[3] = e3i+w3i;
  xr[7] = e3r-w3r; xi[7] = e3i-w3i;
}

// ---------------- K1: STFT magnitude + moment atomics ------------------------
// 4 waves/WG, each wave = one FRAME PAIR (frames 2p, 2p+1) packed a+ib.
// Private LDS slice per wave -> NO __syncthreads (DS ops in-order per wave).
__global__ __launch_bounds__(256) void k_stft(const float* __restrict__ audio,
    const float* __restrict__ win_dr, const float2* __restrict__ lut,
    unsigned short* __restrict__ spec, float* __restrict__ sums){
  __shared__ float re[4][576], im[4][576];
  const int wid = threadIdx.x >> 6;
  const int L = threadIdx.x & 63;
  float* RE = re[wid];
  float* IM = im[wid];
  const int pair = blockIdx.x*4 + wid;        // 0..69631
  const int fr0 = pair*2;
  const int b0 = fr0/17, t0 = fr0 - b0*17;
  const int fr1 = fr0 + 1;
  const int b1 = fr1/17, t1 = fr1 - b1*17;
  const float* sA = audio + (size_t)b0*3200 + t0*160;
  const float* sB = audio + (size_t)b1*3200 + t1*160;
  float xr[8], xi[8];
  {
    float4 w0 = *(const float4*)(win_dr + 8*L);
    float4 w1 = *(const float4*)(win_dr + 8*L + 4);
    float wv[8] = {w0.x,w0.y,w0.z,w0.w,w1.x,w1.y,w1.z,w1.w};
    #pragma unroll
    for (int e = 0; e < 8; e++){
      int idx = 8*L + e;
      int r9 = ((idx & 7) << 6) | (idx & 56) | (idx >> 6);
      xr[e] = sA[r9]*wv[e];                   // frame A -> real
      xi[e] = sB[r9]*wv[e];                   // frame B -> imag
    }
  }
  dft8(xr, xi);
  #pragma unroll
  for (int f = 0; f < 8; f++){
    int i = 8*L + f, loc = i + (i >> 3);
    RE[loc] = xr[f]; IM[loc] = xi[f];
  }
  // stage 1: m=64
  {
    int j = L & 7, g = L >> 3;
    int base = g*64 + j;
    #pragma unroll
    for (int e = 0; e < 8; e++){
      int i = base + 8*e, loc = i + (i >> 3);
      xr[e] = RE[loc]; xi[e] = IM[loc];
    }
    #pragma unroll
    for (int e = 1; e < 8; e++){
      float2 w = lut[8*j*e];
      float a = xr[e], bb = xi[e];
      xr[e] = a*w.x - bb*w.y;
      xi[e] = a*w.y + bb*w.x;
    }
    dft8(xr, xi);
    #pragma unroll
    for (int f = 0; f < 8; f++){
      int i = base + 8*f, loc = i + (i >> 3);
      RE[loc] = xr[f]; IM[loc] = xi[f];
    }
  }
  // stage 2: m=512, lane L -> Z[k = L + 64f]
  {
    int j = L;
    #pragma unroll
    for (int e = 0; e < 8; e++){
      int loc = j + (j >> 3) + 72*e;
      xr[e] = RE[loc]; xi[e] = IM[loc];
    }
    #pragma unroll
    for (int e = 1; e < 8; e++){
      float2 w = lut[j*e];
      float a = xr[e], bb = xi[e];
      xr[e] = a*w.x - bb*w.y;
      xi[e] = a*w.y + bb*w.x;
    }
    dft8(xr, xi);
  }
  // store Z in natural-k order (intra-wave in-order DS: no barrier needed)
  #pragma unroll
  for (int f = 0; f < 8; f++){
    int k = L + 64*f, loc = k + (k >> 3);
    RE[loc] = xr[f]; IM[loc] = xi[f];
  }
  // unpack: Xa = (Z[k]+conj(Z[512-k]))/2 ; Xb = (Z[k]-conj(Z[512-k]))/(2i)
  unsigned short* dA = spec + (size_t)b0*4384 + t0*257;
  unsigned short* dB = spec + (size_t)b1*4384 + t1*257;
  float s1A = 0.f, s2A = 0.f, s1B = 0.f, s2B = 0.f;
  #pragma unroll
  for (int f = 0; f < 5; f++){
    int k = L + 64*f;
    if (f < 4 || L == 0){
      int kp = (512 - k) & 511;
      float zr = RE[k + (k >> 3)],  zi = IM[k + (k >> 3)];
      float wr = RE[kp + (kp >> 3)], wi = IM[kp + (kp >> 3)];
      float ar = zr + wr, ai = zi - wi;
      float br = zi + wi, bi = wr - zr;
      float magA = 0.5f*sqrtf(ar*ar + ai*ai);
      float magB = 0.5f*sqrtf(br*br + bi*bi);
      dA[k] = f2bf(magA);
      dB[k] = f2bf(magB);
      s1A += magA; s2A += magA*magA;
      s1B += magB; s2B += magB*magB;
    }
  }
  // wave-reduce the four sums, one atomic each from lane 0
  #pragma unroll
  for (int off = 32; off > 0; off >>= 1){
    s1A += __shfl_down(s1A, off);
    s2A += __shfl_down(s2A, off);
    s1B += __shfl_down(s1B, off);
    s2B += __shfl_down(s2B, off);
  }
  if (L == 0){
    atomicAdd(&sums[b0], s1A);
    atomicAdd(&sums[8192 + b0], s2A);
    atomicAdd(&sums[b1], s1B);
    atomicAdd(&sums[8192 + b1], s2B);
  }
  if (t0 == 0 && L < 15) spec[(size_t)b0*4384 + 4369 + L] = 0;
  if (t1 == 0 && L < 15) spec[(size_t)b1*4384 + 4369 + L] = 0;
}

// ---------------- K4: partial GEMM spec·Dᵀ, MFMA, 64 samples/WG, prefetch ----
__global__ __launch_bounds__(128) void k_gemm(const unsigned short* __restrict__ spec,
    const unsigned short* __restrict__ Dbf, float* __restrict__ part){
  const int mtile = blockIdx.x;               // 0..127
  const int ks = blockIdx.y;                  // 0..3
  const int wv = threadIdx.x >> 6;
  const int lane = threadIdx.x & 63;
  const int c = lane & 15, q = lane >> 4;
  const int mbase = mtile*64 + wv*32;
  const unsigned short* ap0 = spec + (size_t)(mbase + c)*4384 + q*8;
  const unsigned short* ap1 = ap0 + (size_t)16*4384;
  const unsigned short* bp  = Dbf + (size_t)c*4384 + q*8;
  const int t0 = ks*35, t1 = (ks == 3) ? 137 : (ks*35 + 35);
  f32x4 acc0[8], acc1[8];
  #pragma unroll
  for (int nt = 0; nt < 8; nt++){
    acc0[nt] = (f32x4){0.f,0.f,0.f,0.f};
    acc1[nt] = (f32x4){0.f,0.f,0.f,0.f};
  }
  int k0 = t0*32;
  bf16x8 aC0 = *(const bf16x8*)(ap0 + k0);
  bf16x8 aC1 = *(const bf16x8*)(ap1 + k0);
  bf16x8 bC[8];
  #pragma unroll
  for (int nt = 0; nt < 8; nt++)
    bC[nt] = *(const bf16x8*)(bp + (size_t)nt*16*4384 + k0);
  for (int tt = t0; tt < t1; tt++){
    const int tn = (tt + 1 < t1) ? tt + 1 : tt;
    const int kn = tn*32;
    bf16x8 aN0 = *(const bf16x8*)(ap0 + kn);
    bf16x8 aN1 = *(const bf16x8*)(ap1 + kn);
    bf16x8 bN[8];
    #pragma unroll
    for (int nt = 0; nt < 8; nt++)
      bN[nt] = *(const bf16x8*)(bp + (size_t)nt*16*4384 + kn);
    #pragma unroll
    for (int nt = 0; nt < 8; nt++){
      acc0[nt] = __builtin_amdgcn_mfma_f32_16x16x32_bf16(aC0, bC[nt], acc0[nt], 0, 0, 0);
      acc1[nt] = __builtin_amdgcn_mfma_f32_16x16x32_bf16(aC1, bC[nt], acc1[nt], 0, 0, 0);
    }
    aC0 = aN0; aC1 = aN1;
    #pragma unroll
    for (int nt = 0; nt < 8; nt++) bC[nt] = bN[nt];
  }
  // C/D: row(m)=q*4+r, col(n)=c -> part[ks][n][m]
  float* base = part + (size_t)ks*1048576 + mbase + q*4;
  #pragma unroll
  for (int nt = 0; nt < 8; nt++){
    *(f32x4*)(base + (size_t)(nt*16 + c)*8192)      = acc0[nt];
    *(f32x4*)(base + (size_t)(nt*16 + c)*8192 + 16) = acc1[nt];
  }
}

// ---------------- K5: LCA, 50 iters. rᵀ = G·aᵀ; G in VGPRs; n-split ---------
// 512 blocks x 128 thr: block = 16 samples; wave wv handles n in [wv*64, wv*64+64).
// a exchanged via double-buffered LDS, ONE barrier per iter.
__global__ __launch_bounds__(128) void k_lca(const float* __restrict__ part,
    const unsigned short* __restrict__ gram_bf, const float* __restrict__ rowsum,
    const float* __restrict__ sums, float* __restrict__ out){
  __shared__ unsigned short A[2][16*136];
  const int tid = threadIdx.x, wv = tid >> 6, lane = tid & 63;
  const int c = lane & 15, q = lane >> 4;
  const int sg = blockIdx.x*16 + c;
  const float S1 = sums[sg], S2 = sums[8192 + sg];
  const float mus = S1 / 4369.0f;
  float var = (S2 - S1*S1/4369.0f) / 4368.0f;
  var = fmaxf(var, 0.0f);
  const float invs = 1.0f / (sqrtf(var) + 1e-8f);
  const int nb = wv*64;
  bf16x8 Gf[4][4];                            // A-frags of G rows [nb, nb+64)
  #pragma unroll
  for (int rt = 0; rt < 4; rt++)
    #pragma unroll
    for (int kt = 0; kt < 4; kt++)
      Gf[rt][kt] = *(const bf16x8*)(gram_bf + (size_t)(nb + rt*16 + c)*136 + kt*32 + q*8);
  f32x4 U[4], Bb[4];
  #pragma unroll
  for (int rt = 0; rt < 4; rt++){
    #pragma unroll
    for (int r = 0; r < 4; r++){
      int n = nb + rt*16 + q*4 + r;
      float S = part[(size_t)n*8192 + sg]
              + part[(size_t)1048576 + (size_t)n*8192 + sg]
              + part[(size_t)2097152 + (size_t)n*8192 + sg]
              + part[(size_t)3145728 + (size_t)n*8192 + sg];
      Bb[rt][r] = invs * (S - mus * rowsum[n]);
      U[rt][r] = 0.0f;
    }
  }
  for (int it = 0; it < 50; it++){
    unsigned short* Ab = A[it & 1];
    #pragma unroll
    for (int rt = 0; rt < 4; rt++){
      ushort4 pk;
      pk.x = f2bf(sshrink(U[rt][0]));
      pk.y = f2bf(sshrink(U[rt][1]));
      pk.z = f2bf(sshrink(U[rt][2]));
      pk.w = f2bf(sshrink(U[rt][3]));
      *(ushort4*)(Ab + c*136 + nb + rt*16 + q*4) = pk;
    }
    __syncthreads();
    bf16x8 af[4];
    #pragma unroll
    for (int kt = 0; kt < 4; kt++)            // B-frag: aᵀ[k][s=c]
      af[kt] = *(const bf16x8*)(Ab + c*136 + kt*32 + q*8);
    f32x4 R[4];
    #pragma unroll
    for (int rt = 0; rt < 4; rt++) R[rt] = (f32x4){0.f,0.f,0.f,0.f};
    #pragma unroll
    for (int rt = 0; rt < 4; rt++)
      #pragma unroll
      for (int kt = 0; kt < 4; kt++)
        R[rt] = __builtin_amdgcn_mfma_f32_16x16x32_bf16(Gf[rt][kt], af[kt], R[rt], 0, 0, 0);
    #pragma unroll
    for (int rt = 0; rt < 4; rt++){
      #pragma unroll
      for (int r = 0; r < 4; r++){
        float u = U[rt][r];
        U[rt][r] = u + (Bb[rt][r] - u - R[rt][r]) * 0.1f;
      }
    }
  }
  #pragma unroll
  for (int rt = 0; rt < 4; rt++){
    float4 o;
    o.x = sshrink(U[rt][0]);
    o.y = sshrink(U[rt][1]);
    o.z = sshrink(U[rt][2]);
    o.w = sshrink(U[rt][3]);
    *(float4*)(out + (size_t)sg*128 + nb + rt*16 + q*4) = o;
  }
}

// ---------------- launch ----------------
extern "C" void kernel_launch(void* const* d_in, const int* in_sizes, int n_in,
                              void* d_out, int out_size, void* d_ws, size_t ws_size,
                              hipStream_t stream){
  const float* audio = (const float*)d_in[0];   // 8192*3200
  const float* D     = (const float*)d_in[1];   // 128*4369
  float* out = (float*)d_out;                   // 8192*128 f32
  char* ws = (char*)d_ws;
  // workspace layout, total ~92.34 MB
  unsigned short* spec   = (unsigned short*)(ws);               // 71,827,456
  float*          part   = (float*)(ws + 71827456);             // 16,777,216
  unsigned short* Dbf    = (unsigned short*)(ws + 88604672);    // 1,122,304
  float*          Dt     = (float*)(ws + 89726976);             // 2,244,608
  unsigned short* gram   = (unsigned short*)(ws + 91971584);    // 34,816
  float*          pg     = (float*)(ws + 92006400);             // 262,144
  float*          rowsum = (float*)(ws + 92268544);             // 512
  float*          sums   = (float*)(ws + 92269056);             // 65,536 (s1 | s2)
  float*          win_dr = (float*)(ws + 92334592);             // 2,048
  float2*         lut    = (float2*)(ws + 92336640);            // 4,096

  hipMemsetAsync(sums, 0, 65536, stream);       // ws is poisoned each launch
  k_tables   <<<2, 256, 0, stream>>>(win_dr, lut);
  k_stft     <<<17408, 256, 0, stream>>>(audio, win_dr, lut, spec, sums);
  k_dprep    <<<128, 256, 0, stream>>>(D, Dbf, Dt, rowsum);
  k_gram_part<<<dim3(128, 4, 1), 128, 0, stream>>>(Dt, pg);
  k_gram_fin <<<128, 128, 0, stream>>>(pg, gram);
  k_gemm     <<<dim3(128, 4, 1), 128, 0, stream>>>(spec, Dbf, part);
  k_lca      <<<512, 128, 0, stream>>>(part, gram, rowsum, sums, out);
}

// Round 3
// 333.079 us; speedup vs baseline: 1.7813x; 1.2310x over previous
//
#include <hip/hip_runtime.h>
#include <hip/hip_bf16.h>
#include <math.h>

// A1SparseCoding: STFT(512,160,hann,center=False) -> |.| -> per-sample norm ->
// LCA (50 iters, lam=0.5, tau=10) -> softshrink(u)
// B=8192, SEG=3200, T=17 frames, F=257 freqs, K=17*257=4369 (pad 4384), N=128 bases.
// spec stored [b][t*257+f]; D's columns permuted identically (dot products invariant).
// STFT: two real frames packed as one complex FFT (a+ib), radix-8 DIT, fp32,
// twiddles/window via v_sin/v_cos (all args < 1 revolution), conj-unpack via shfl.

typedef short bf16x8 __attribute__((ext_vector_type(8)));
typedef float f32x4  __attribute__((ext_vector_type(4)));

#define TWO_PI_OVER_512 0.01227184630f
#define TWO_PI_OVER_64  0.09817477042f

__device__ __forceinline__ unsigned short f2bf(float f){
  unsigned int u = __float_as_uint(f);
  u += 0x7FFFu + ((u >> 16) & 1u);      // RNE; inputs finite
  return (unsigned short)(u >> 16);
}
__device__ __forceinline__ float sshrink(float u){
  float a = fabsf(u) - 0.5f;
  return a > 0.0f ? copysignf(a, u) : 0.0f;
}
// LDS slot for element i: pad so octet stride (9) is odd and 64-el row stride
// (77) is odd mod 16 -> even bank spread for stride-8 and stride-64 access.
__device__ __forceinline__ int slot(int i){ return i + (i >> 3) + 5*(i >> 6); }

// ---------------- P1: D prep: Dbf[n][k'] bf16 via LDS permute + rowsum -------
__global__ __launch_bounds__(256) void k_dprep(const float* __restrict__ D,
    unsigned short* __restrict__ Dbf, float* __restrict__ rowsum){
  __shared__ float row[4369];
  __shared__ float rs[256];
  const int n = blockIdx.x, tid = threadIdx.x;
  float acc = 0.0f;
  for (int k = tid; k < 4369; k += 256){
    float v = D[(size_t)n*4369 + k];          // coalesced
    row[k] = v;
    acc += v;
  }
  rs[tid] = acc;
  __syncthreads();
  #pragma unroll
  for (int s = 128; s > 0; s >>= 1){
    if (tid < s) rs[tid] += rs[tid + s];
    __syncthreads();
  }
  if (tid == 0) rowsum[n] = rs[0];
  // permuted bf16 row: k' = t*257+f  <-  src = f*17+t ; packed ushort4 stores
  for (int i = tid; i < 1096; i += 256){
    int k0 = i*4;
    ushort4 pk;
    unsigned short v[4];
    #pragma unroll
    for (int u = 0; u < 4; u++){
      int kp = k0 + u;
      unsigned short r = 0;
      if (kp < 4369){
        int t = kp / 257, f = kp - t*257;
        r = f2bf(row[f*17 + t]);
      }
      v[u] = r;
    }
    pk.x = v[0]; pk.y = v[1]; pk.z = v[2]; pk.w = v[3];
    *(ushort4*)(Dbf + (size_t)n*4384 + k0) = pk;
  }
}

// ---------------- P2: gram = Dbf·Dbfᵀ partials via MFMA (k-split 8) ----------
__global__ __launch_bounds__(64) void k_gram_mm(const unsigned short* __restrict__ Dbf,
    float* __restrict__ pgram){
  const int x = blockIdx.x;                   // 16-row strip, 0..7
  const int ks = blockIdx.y;                  // 0..7
  const int lane = threadIdx.x;
  const int c = lane & 15, q = lane >> 4;
  const unsigned short* ap = Dbf + (size_t)(x*16 + c)*4384 + q*8;
  const unsigned short* bp = Dbf + (size_t)c*4384 + q*8;
  const int t0 = ks*17, t1 = (ks == 7) ? 137 : t0 + 17;
  f32x4 acc[8];
  #pragma unroll
  for (int nt = 0; nt < 8; nt++) acc[nt] = (f32x4){0.f,0.f,0.f,0.f};
  for (int tt = t0; tt < t1; tt++){
    const int k0 = tt*32;
    bf16x8 af = *(const bf16x8*)(ap + k0);
    #pragma unroll
    for (int nt = 0; nt < 8; nt++){
      bf16x8 bfr = *(const bf16x8*)(bp + (size_t)nt*16*4384 + k0);
      acc[nt] = __builtin_amdgcn_mfma_f32_16x16x32_bf16(af, bfr, acc[nt], 0, 0, 0);
    }
  }
  // C layout: row = q*4+r (gram row within strip), col = c (gram col within nt)
  #pragma unroll
  for (int nt = 0; nt < 8; nt++)
    #pragma unroll
    for (int r = 0; r < 4; r++)
      pgram[(size_t)(ks*128 + x*16 + q*4 + r)*128 + nt*16 + c] = acc[nt][r];
}
// deterministic fixed-order sum -> exactly symmetric (MFMA k-order identical for (x,y)/(y,x))
__global__ __launch_bounds__(128) void k_gram_fin(const float* __restrict__ pgram,
    unsigned short* __restrict__ gram_bf){
  const int x = blockIdx.x, y = threadIdx.x;
  float g = ((pgram[(size_t)x*128+y]        + pgram[(size_t)(128+x)*128+y])
          +  (pgram[(size_t)(256+x)*128+y]  + pgram[(size_t)(384+x)*128+y]))
          + ((pgram[(size_t)(512+x)*128+y]  + pgram[(size_t)(640+x)*128+y])
          +  (pgram[(size_t)(768+x)*128+y]  + pgram[(size_t)(896+x)*128+y]));
  if (x == y) g -= 1.0f;
  gram_bf[x*136 + y] = f2bf(g);
}

// ---------------- radix-8 butterfly (DIT), in registers ----------------------
__device__ __forceinline__ void dft8(float xr[8], float xi[8]){
  const float C = 0.70710678118654752f;
  float t0r = xr[0]+xr[4], t0i = xi[0]+xi[4];
  float t1r = xr[0]-xr[4], t1i = xi[0]-xi[4];
  float t2r = xr[2]+xr[6], t2i = xi[2]+xi[6];
  float t3r = xr[2]-xr[6], t3i = xi[2]-xi[6];
  float e0r = t0r+t2r, e0i = t0i+t2i;
  float e2r = t0r-t2r, e2i = t0i-t2i;
  float e1r = t1r+t3i, e1i = t1i-t3r;
  float e3r = t1r-t3i, e3i = t1i+t3r;
  float s0r = xr[1]+xr[5], s0i = xi[1]+xi[5];
  float s1r = xr[1]-xr[5], s1i = xi[1]-xi[5];
  float s2r = xr[3]+xr[7], s2i = xi[3]+xi[7];
  float s3r = xr[3]-xr[7], s3i = xi[3]-xi[7];
  float o0r = s0r+s2r, o0i = s0i+s2i;
  float o2r = s0r-s2r, o2i = s0i-s2i;
  float o1r = s1r+s3i, o1i = s1i-s3r;
  float o3r = s1r-s3i, o3i = s1i+s3r;
  xr[0] = e0r+o0r; xi[0] = e0i+o0i;
  xr[4] = e0r-o0r; xi[4] = e0i-o0i;
  float w1r = C*(o1r+o1i), w1i = C*(o1i-o1r);
  xr[1] = e1r+w1r; xi[1] = e1i+w1i;
  xr[5] = e1r-w1r; xi[5] = e1i-w1i;
  xr[2] = e2r+o2i; xi[2] = e2i-o2r;
  xr[6] = e2r-o2i; xi[6] = e2i+o2r;
  float w3r = C*(o3i-o3r), w3i = -C*(o3r+o3i);
  xr[3] = e3r+w3r; xi[3] = e3i+w3i;
  xr[7] = e3r-w3r; xi[7] = e3i-w3i;
}

// ---------------- K1: STFT magnitude + moment atomics ------------------------
// 4 waves/WG, each wave = one FRAME PAIR packed a+ib; private LDS slice, no barriers.
__global__ __launch_bounds__(256) void k_stft(const float* __restrict__ audio,
    unsigned short* __restrict__ spec, float* __restrict__ sums){
  __shared__ float2 zb[4][616];
  const int wid = threadIdx.x >> 6;
  const int L = threadIdx.x & 63;
  float2* Z = zb[wid];
  const int pair = blockIdx.x*4 + wid;        // 0..69631
  const int fr0 = pair*2;
  const int b0 = fr0/17, t0 = fr0 - b0*17;
  const int fr1 = fr0 + 1;
  const int b1 = fr1/17, t1 = fr1 - b1*17;
  const float* sA = audio + (size_t)b0*3200 + t0*160;
  const float* sB = audio + (size_t)b1*3200 + t1*160;
  float xr[8], xi[8];
  // fused digit-reversed load + window (computed) ; idx=8L+e -> r9 = baseRev+64e
  {
    const int baseRev = ((L & 7) << 3) | (L >> 3);
    #pragma unroll
    for (int e = 0; e < 8; e++){
      int r9 = baseRev + (e << 6);
      float w = 0.5f - 0.5f*__cosf((float)r9 * TWO_PI_OVER_512);
      xr[e] = sA[r9]*w;
      xi[e] = sB[r9]*w;
    }
  }
  dft8(xr, xi);
  {
    int s0 = 9*L + 5*(L >> 3);                // slot(8L), e contiguous
    #pragma unroll
    for (int e = 0; e < 8; e++) Z[s0 + e] = make_float2(xr[e], xi[e]);
  }
  // stage 1: i = g*64 + j + 8e -> slot = 77g + j + 9e
  {
    int j = L & 7, g = L >> 3;
    int sb = 77*g + j;
    #pragma unroll
    for (int e = 0; e < 8; e++){
      float2 z = Z[sb + 9*e];
      xr[e] = z.x; xi[e] = z.y;
    }
    #pragma unroll
    for (int e = 1; e < 8; e++){
      float t = (float)(j*e) * TWO_PI_OVER_64;
      float cw = __cosf(t), sw = __sinf(t);   // W = cw - i*sw
      float a = xr[e], b = xi[e];
      xr[e] = a*cw + b*sw;
      xi[e] = b*cw - a*sw;
    }
    dft8(xr, xi);
    #pragma unroll
    for (int e = 0; e < 8; e++) Z[sb + 9*e] = make_float2(xr[e], xi[e]);
  }
  // stage 2: i = L + 64e -> slot = L + (L>>3) + 77e ; lane L ends with Z[k=L+64f]
  {
    int sb = L + (L >> 3);
    #pragma unroll
    for (int e = 0; e < 8; e++){
      float2 z = Z[sb + 77*e];
      xr[e] = z.x; xi[e] = z.y;
    }
    #pragma unroll
    for (int e = 1; e < 8; e++){
      float t = (float)(L*e) * TWO_PI_OVER_512;
      float cw = __cosf(t), sw = __sinf(t);
      float a = xr[e], b = xi[e];
      xr[e] = a*cw + b*sw;
      xi[e] = b*cw - a*sw;
    }
    dft8(xr, xi);
  }
  // conj-partner exchange: partner of k=L+64f is lane (64-L)&63, reg 7-f (L>=1)
  float pr[4], pi[4];
  {
    const int partner = (64 - L) & 63;
    #pragma unroll
    for (int f = 0; f < 4; f++){
      pr[f] = __shfl(xr[7-f], partner);
      pi[f] = __shfl(xi[7-f], partner);
    }
    if (L == 0){                              // lane 0: partner regs are own (8-f)&7
      pr[0] = xr[0]; pi[0] = xi[0];
      pr[1] = xr[7]; pi[1] = xi[7];
      pr[2] = xr[6]; pi[2] = xi[6];
      pr[3] = xr[5]; pi[3] = xi[5];
    }
  }
  unsigned short* dA = spec + (size_t)b0*4384 + t0*257;
  unsigned short* dB = spec + (size_t)b1*4384 + t1*257;
  float s1A = 0.f, s2A = 0.f, s1B = 0.f, s2B = 0.f;
  #pragma unroll
  for (int f = 0; f < 4; f++){
    int k = L + 64*f;
    float ar = xr[f] + pr[f], ai = xi[f] - pi[f];
    float br = xi[f] + pi[f], bi = pr[f] - xr[f];
    float magA = 0.5f*sqrtf(ar*ar + ai*ai);
    float magB = 0.5f*sqrtf(br*br + bi*bi);
    dA[k] = f2bf(magA);
    dB[k] = f2bf(magB);
    s1A += magA; s2A += magA*magA;
    s1B += magB; s2B += magB*magB;
  }
  if (L == 0){                                // k=256: Xa=Re(Z[256]), Xb=Im(Z[256])
    float magA = fabsf(xr[4]);
    float magB = fabsf(xi[4]);
    dA[256] = f2bf(magA);
    dB[256] = f2bf(magB);
    s1A += magA; s2A += magA*magA;
    s1B += magB; s2B += magB*magB;
  }
  #pragma unroll
  for (int off = 32; off > 0; off >>= 1){
    s1A += __shfl_down(s1A, off);
    s2A += __shfl_down(s2A, off);
    s1B += __shfl_down(s1B, off);
    s2B += __shfl_down(s2B, off);
  }
  if (L == 0){
    atomicAdd(&sums[b0], s1A);
    atomicAdd(&sums[8192 + b0], s2A);
    atomicAdd(&sums[b1], s1B);
    atomicAdd(&sums[8192 + b1], s2B);
  }
  if (t0 == 0 && L < 15) spec[(size_t)b0*4384 + 4369 + L] = 0;
  if (t1 == 0 && L < 15) spec[(size_t)b1*4384 + 4369 + L] = 0;
}

// ---------------- K4: partial GEMM spec·Dᵀ, MFMA, 16 samples/wave, prefetch --
__global__ __launch_bounds__(128) void k_gemm(const unsigned short* __restrict__ spec,
    const unsigned short* __restrict__ Dbf, float* __restrict__ part){
  const int mtile = blockIdx.x;               // 0..255
  const int ks = blockIdx.y;                  // 0..3
  const int wv = threadIdx.x >> 6;
  const int lane = threadIdx.x & 63;
  const int c = lane & 15, q = lane >> 4;
  const int m0 = mtile*32 + wv*16;
  const unsigned short* ap = spec + (size_t)(m0 + c)*4384 + q*8;
  const unsigned short* bp = Dbf + (size_t)c*4384 + q*8;
  const int t0 = ks*35, t1 = (ks == 3) ? 137 : (ks*35 + 35);
  f32x4 acc[8];
  #pragma unroll
  for (int nt = 0; nt < 8; nt++) acc[nt] = (f32x4){0.f,0.f,0.f,0.f};
  int k0 = t0*32;
  bf16x8 aC = *(const bf16x8*)(ap + k0);
  bf16x8 bC[8];
  #pragma unroll
  for (int nt = 0; nt < 8; nt++)
    bC[nt] = *(const bf16x8*)(bp + (size_t)nt*16*4384 + k0);
  for (int tt = t0; tt < t1; tt++){
    const int tn = (tt + 1 < t1) ? tt + 1 : tt;
    const int kn = tn*32;
    bf16x8 aN = *(const bf16x8*)(ap + kn);
    bf16x8 bN[8];
    #pragma unroll
    for (int nt = 0; nt < 8; nt++)
      bN[nt] = *(const bf16x8*)(bp + (size_t)nt*16*4384 + kn);
    #pragma unroll
    for (int nt = 0; nt < 8; nt++)
      acc[nt] = __builtin_amdgcn_mfma_f32_16x16x32_bf16(aC, bC[nt], acc[nt], 0, 0, 0);
    aC = aN;
    #pragma unroll
    for (int nt = 0; nt < 8; nt++) bC[nt] = bN[nt];
  }
  float* base = part + (size_t)ks*1048576 + m0 + q*4;
  #pragma unroll
  for (int nt = 0; nt < 8; nt++)
    *(f32x4*)(base + (size_t)(nt*16 + c)*8192) = acc[nt];
}

// ---------------- K5: LCA, 50 iters. rᵀ = G·aᵀ; 4 waves x 32 gram rows ------
// 512 blocks x 256 thr: block = 16 samples; wave wv owns rows [wv*32, wv*32+32).
// a exchanged via double-buffered LDS, ONE barrier per iter.
__global__ __launch_bounds__(256) void k_lca(const float* __restrict__ part,
    const unsigned short* __restrict__ gram_bf, const float* __restrict__ rowsum,
    const float* __restrict__ sums, float* __restrict__ out){
  __shared__ unsigned short A[2][16*136];
  const int tid = threadIdx.x, wv = tid >> 6, lane = tid & 63;
  const int c = lane & 15, q = lane >> 4;
  const int sg = blockIdx.x*16 + c;
  const float S1 = sums[sg], S2 = sums[8192 + sg];
  const float mus = S1 / 4369.0f;
  float var = (S2 - S1*S1/4369.0f) / 4368.0f;
  var = fmaxf(var, 0.0f);
  const float invs = 1.0f / (sqrtf(var) + 1e-8f);
  const int nb = wv*32;
  bf16x8 Gf[2][4];                            // A-frags of G rows [nb, nb+32)
  #pragma unroll
  for (int rt = 0; rt < 2; rt++)
    #pragma unroll
    for (int kt = 0; kt < 4; kt++)
      Gf[rt][kt] = *(const bf16x8*)(gram_bf + (size_t)(nb + rt*16 + c)*136 + kt*32 + q*8);
  f32x4 U[2], Bb[2];
  #pragma unroll
  for (int rt = 0; rt < 2; rt++){
    #pragma unroll
    for (int r = 0; r < 4; r++){
      int n = nb + rt*16 + q*4 + r;
      float S = part[(size_t)n*8192 + sg]
              + part[(size_t)1048576 + (size_t)n*8192 + sg]
              + part[(size_t)2097152 + (size_t)n*8192 + sg]
              + part[(size_t)3145728 + (size_t)n*8192 + sg];
      Bb[rt][r] = invs * (S - mus * rowsum[n]);
      U[rt][r] = 0.0f;
    }
  }
  for (int it = 0; it < 50; it++){
    unsigned short* Ab = A[it & 1];
    #pragma unroll
    for (int rt = 0; rt < 2; rt++){
      ushort4 pk;
      pk.x = f2bf(sshrink(U[rt][0]));
      pk.y = f2bf(sshrink(U[rt][1]));
      pk.z = f2bf(sshrink(U[rt][2]));
      pk.w = f2bf(sshrink(U[rt][3]));
      *(ushort4*)(Ab + c*136 + nb + rt*16 + q*4) = pk;
    }
    __syncthreads();
    bf16x8 af[4];
    #pragma unroll
    for (int kt = 0; kt < 4; kt++)            // B-frag: aᵀ[k][sample=c]
      af[kt] = *(const bf16x8*)(Ab + c*136 + kt*32 + q*8);
    f32x4 R[2];
    R[0] = (f32x4){0.f,0.f,0.f,0.f};
    R[1] = (f32x4){0.f,0.f,0.f,0.f};
    #pragma unroll
    for (int kt = 0; kt < 4; kt++)            // kt outer: R[0],R[1] chains interleave
      #pragma unroll
      for (int rt = 0; rt < 2; rt++)
        R[rt] = __builtin_amdgcn_mfma_f32_16x16x32_bf16(Gf[rt][kt], af[kt], R[rt], 0, 0, 0);
    #pragma unroll
    for (int rt = 0; rt < 2; rt++){
      #pragma unroll
      for (int r = 0; r < 4; r++){
        float u = U[rt][r];
        U[rt][r] = u + (Bb[rt][r] - u - R[rt][r]) * 0.1f;
      }
    }
  }
  #pragma unroll
  for (int rt = 0; rt < 2; rt++){
    float4 o;
    o.x = sshrink(U[rt][0]);
    o.y = sshrink(U[rt][1]);
    o.z = sshrink(U[rt][2]);
    o.w = sshrink(U[rt][3]);
    *(float4*)(out + (size_t)sg*128 + nb + rt*16 + q*4) = o;
  }
}

// ---------------- launch ----------------
extern "C" void kernel_launch(void* const* d_in, const int* in_sizes, int n_in,
                              void* d_out, int out_size, void* d_ws, size_t ws_size,
                              hipStream_t stream){
  const float* audio = (const float*)d_in[0];   // 8192*3200
  const float* D     = (const float*)d_in[1];   // 128*4369
  float* out = (float*)d_out;                   // 8192*128 f32
  char* ws = (char*)d_ws;
  // workspace layout, total ~90.4 MB
  unsigned short* spec   = (unsigned short*)(ws);               // 71,827,456
  float*          part   = (float*)(ws + 71827456);             // 16,777,216
  unsigned short* Dbf    = (unsigned short*)(ws + 88604672);    // 1,122,304
  unsigned short* gram   = (unsigned short*)(ws + 89726976);    // 34,816
  float*          pgram  = (float*)(ws + 89761792);             // 524,288
  float*          rowsum = (float*)(ws + 90286080);             // 512
  float*          sums   = (float*)(ws + 90286592);             // 65,536 (s1 | s2)

  hipMemsetAsync(sums, 0, 65536, stream);       // ws is poisoned each launch
  k_stft    <<<17408, 256, 0, stream>>>(audio, spec, sums);
  k_dprep   <<<128, 256, 0, stream>>>(D, Dbf, rowsum);
  k_gram_mm <<<dim3(8, 8, 1), 64, 0, stream>>>(Dbf, pgram);
  k_gram_fin<<<128, 128, 0, stream>>>(pgram, gram);
  k_gemm    <<<dim3(256, 4, 1), 128, 0, stream>>>(spec, Dbf, part);
  k_lca     <<<512, 256, 0, stream>>>(part, gram, rowsum, sums, out);
}